// Round 4
// baseline (126.651 us; speedup 1.0000x reference)
//
#include <hip/hip_runtime.h>
#include <math.h>

constexpr int kD   = 128;
constexpr int kE   = 256;
constexpr int kTok = 2048;
constexpr int kGrid2 = 512;   // node-2 grid: 2 blocks per expert (output halves)

// ---------------- K1: gate (logits -> softmax -> top2) ----------------------
// 512 blocks x 256 threads; block handles 4 tokens; thread t = expert t.
// Also zeroes the grid-barrier counter used by node 2.
__global__ __launch_bounds__(256) void k_gate(
    const float* __restrict__ x, const float* __restrict__ gate_w,
    const float* __restrict__ gate_b,
    float2* __restrict__ tokinfo, int* __restrict__ top2,
    int* __restrict__ barrier_ctr)
{
    const int b  = blockIdx.x;
    const int t  = threadIdx.x;
    const int wv = t >> 6, ln = t & 63;

    if (b == 0 && t == 0) *barrier_ctr = 0;   // re-armed every launch

    __shared__ float xsT[kD][4];
    __shared__ float partf[4][4];
    __shared__ int   parti[4][4];
    __shared__ int   pi0s[4];
    __shared__ float pv0s[4];

    {
        const float2 v = *(const float2*)(x + ((size_t)(b * 4 + wv)) * kD + ln * 2);
        xsT[ln * 2 + 0][wv] = v.x;
        xsT[ln * 2 + 1][wv] = v.y;
    }
    __syncthreads();

    float lg[4];
    {
        const float bias = gate_b[t];
        lg[0] = lg[1] = lg[2] = lg[3] = bias;
    }
    #pragma unroll 8
    for (int d = 0; d < kD; ++d) {
        const float w = gate_w[d * kE + t];
        const float4 xv = *(const float4*)&xsT[d][0];
        lg[0] = fmaf(xv.x, w, lg[0]);
        lg[1] = fmaf(xv.y, w, lg[1]);
        lg[2] = fmaf(xv.z, w, lg[2]);
        lg[3] = fmaf(xv.w, w, lg[3]);
    }

    // max over 256 experts
    float m[4];
    #pragma unroll
    for (int j = 0; j < 4; ++j) m[j] = lg[j];
    #pragma unroll
    for (int s = 1; s < 64; s <<= 1) {
        #pragma unroll
        for (int j = 0; j < 4; ++j) m[j] = fmaxf(m[j], __shfl_xor(m[j], s));
    }
    if (ln == 0) {
        #pragma unroll
        for (int j = 0; j < 4; ++j) partf[wv][j] = m[j];
    }
    __syncthreads();
    float mx[4];
    #pragma unroll
    for (int j = 0; j < 4; ++j)
        mx[j] = fmaxf(fmaxf(partf[0][j], partf[1][j]), fmaxf(partf[2][j], partf[3][j]));
    __syncthreads();

    // sum of exp
    float ex[4], sm[4];
    #pragma unroll
    for (int j = 0; j < 4; ++j) { ex[j] = __expf(lg[j] - mx[j]); sm[j] = ex[j]; }
    #pragma unroll
    for (int s = 1; s < 64; s <<= 1) {
        #pragma unroll
        for (int j = 0; j < 4; ++j) sm[j] += __shfl_xor(sm[j], s);
    }
    if (ln == 0) {
        #pragma unroll
        for (int j = 0; j < 4; ++j) partf[wv][j] = sm[j];
    }
    __syncthreads();
    float p[4];
    #pragma unroll
    for (int j = 0; j < 4; ++j) {
        const float tot = partf[0][j] + partf[1][j] + partf[2][j] + partf[3][j];
        p[j] = ex[j] / tot;
    }
    __syncthreads();

    // argmax pass 1 (ties -> lower index)
    float v[4]; int ix[4];
    #pragma unroll
    for (int j = 0; j < 4; ++j) { v[j] = p[j]; ix[j] = t; }
    #pragma unroll
    for (int s = 1; s < 64; s <<= 1) {
        #pragma unroll
        for (int j = 0; j < 4; ++j) {
            const float ov = __shfl_xor(v[j], s);
            const int   oi = __shfl_xor(ix[j], s);
            if (ov > v[j] || (ov == v[j] && oi < ix[j])) { v[j] = ov; ix[j] = oi; }
        }
    }
    if (ln == 0) {
        #pragma unroll
        for (int j = 0; j < 4; ++j) { partf[wv][j] = v[j]; parti[wv][j] = ix[j]; }
    }
    __syncthreads();
    if (t < 4) {
        const int j = t;
        float bv = partf[0][j]; int bi = parti[0][j];
        #pragma unroll
        for (int w = 1; w < 4; ++w) {
            const float ov = partf[w][j]; const int oi = parti[w][j];
            if (ov > bv || (ov == bv && oi < bi)) { bv = ov; bi = oi; }
        }
        pv0s[j] = bv; pi0s[j] = bi;
    }
    __syncthreads();

    // argmax pass 2 (mask winner)
    #pragma unroll
    for (int j = 0; j < 4; ++j) {
        v[j] = (t == pi0s[j]) ? -INFINITY : p[j];
        ix[j] = t;
    }
    #pragma unroll
    for (int s = 1; s < 64; s <<= 1) {
        #pragma unroll
        for (int j = 0; j < 4; ++j) {
            const float ov = __shfl_xor(v[j], s);
            const int   oi = __shfl_xor(ix[j], s);
            if (ov > v[j] || (ov == v[j] && oi < ix[j])) { v[j] = ov; ix[j] = oi; }
        }
    }
    if (ln == 0) {
        #pragma unroll
        for (int j = 0; j < 4; ++j) { partf[wv][j] = v[j]; parti[wv][j] = ix[j]; }
    }
    __syncthreads();
    if (t < 4) {
        const int j = t;
        float bv = partf[0][j]; int bi = parti[0][j];
        #pragma unroll
        for (int w = 1; w < 4; ++w) {
            const float ov = partf[w][j]; const int oi = parti[w][j];
            if (ov > bv || (ov == bv && oi < bi)) { bv = ov; bi = oi; }
        }
        const int tok = b * 4 + j;
        const float v0 = pv0s[j], v1 = bv;
        const float den = v0 + v1 + 1e-6f;
        tokinfo[tok] = make_float2(v0 / den, v1 / den);
        top2[tok] = pi0s[j] | (bi << 8);
    }
}

// ---------------- K2: fused expert halves + grid barrier + SwiGLU -----------
// 512 blocks x 256 threads, 2 blocks/CU co-resident (manual grid barrier OK).
// Phase 1: block (e = bid>>1, h = bid&1) computes output-half h of expert e's
//          matvecs for its assigned tokens. Phase 2: block handles 4 tokens'
//          SwiGLU + consensus.
__global__ __launch_bounds__(256, 2) void k_fused(
    const float* __restrict__ x, const float* __restrict__ expert_w,
    const int* __restrict__ top2, const float2* __restrict__ tokinfo,
    const float* __restrict__ w1m, const float* __restrict__ b1,
    const float* __restrict__ w2m, const float* __restrict__ b2,
    float* __restrict__ ybuf, int* __restrict__ barrier_ctr,
    float* __restrict__ out_avg, float* __restrict__ out_cons)
{
    const int bid = blockIdx.x;
    const int t   = threadIdx.x;

    // ---- phase-1 LDS ----
    __shared__ float Wh[kD][64];      // 32 KB: half of W_e (columns h*64..)
    __shared__ float xs[16][132];     // padded stride vs 128: kills 4-way bank conflict
    __shared__ int   llist[kTok];     // 8 KB
    __shared__ int   lcount;
    // ---- phase-2 LDS ----
    __shared__ float  ys[4 * 2 * kD];
    __shared__ float  wvT[kD][4];
    __shared__ float  vvs[4][kD];
    __shared__ float  os[4][kD];
    __shared__ float2 ti[4];

    const int e = bid >> 1;
    const int h = bid & 1;

    if (t == 0) lcount = 0;
    __syncthreads();

    // scan routing -> local list
    for (int i = t; i < kTok; i += 256) {
        const int pk = top2[i];
        if ((pk & 0xFF) == e)        llist[atomicAdd(&lcount, 1)] = i * 2;
        if (((pk >> 8) & 0xFF) == e) llist[atomicAdd(&lcount, 1)] = i * 2 + 1;
    }

    // stage half of expert weights: Wh[r][c] = W_e[r][h*64 + c]
    {
        const float* Wg = expert_w + (size_t)e * kD * kD + h * 64;
        #pragma unroll
        for (int k = 0; k < 8; ++k) {
            const int f  = k * 256 + t;      // float4 index, 2048 total
            const int r  = f >> 4;
            const int c4 = (f & 15) * 4;
            *(float4*)&Wh[r][c4] = *(const float4*)&Wg[(size_t)r * kD + c4];
        }
    }
    __syncthreads();
    const int n = lcount;

    // grouped matvecs: 16 groups of 16 lanes; lane covers 4 of 64 outputs
    const int grp = t >> 4, l = t & 15;
    for (int base = 0; base < n; base += 16) {
        const int idx = base + grp;
        const bool valid = idx < n;
        int tok = 0, slot = 0;
        if (valid) {
            const int ev = llist[idx];
            tok = ev >> 1; slot = ev & 1;
            const float* xr = &x[(size_t)tok * kD + l * 8];
            *(float4*)&xs[grp][l * 8]     = *(const float4*)&xr[0];
            *(float4*)&xs[grp][l * 8 + 4] = *(const float4*)&xr[4];
        }
        __syncthreads();

        if (valid) {
            float4 a = make_float4(0.f, 0.f, 0.f, 0.f);
            #pragma unroll 4
            for (int d = 0; d < kD; ++d) {
                const float xv = xs[grp][d];
                const float4 w4 = *(const float4*)&Wh[d][l * 4];
                a.x = fmaf(w4.x, xv, a.x);
                a.y = fmaf(w4.y, xv, a.y);
                a.z = fmaf(w4.z, xv, a.z);
                a.w = fmaf(w4.w, xv, a.w);
            }
            *(float4*)&ybuf[((size_t)tok * 2 + slot) * kD + h * 64 + l * 4] = a;
        }
        __syncthreads();
    }

    // ---- grid barrier (all 512 blocks co-resident by construction) ----
    __syncthreads();
    __threadfence();
    if (t == 0) {
        __hip_atomic_fetch_add(barrier_ctr, 1, __ATOMIC_ACQ_REL, __HIP_MEMORY_SCOPE_AGENT);
        while (__hip_atomic_load(barrier_ctr, __ATOMIC_ACQUIRE, __HIP_MEMORY_SCOPE_AGENT) < kGrid2)
            __builtin_amdgcn_s_sleep(8);
    }
    __syncthreads();
    __threadfence();

    // ---- phase 2: SwiGLU + consensus for 4 tokens ----
    const int tok0 = bid * 4;

    *(float4*)&ys[t * 4] = *(const float4*)&ybuf[(size_t)tok0 * 2 * kD + t * 4];
    if (t < 4) ti[t] = tokinfo[tok0 + t];
    __syncthreads();

    #pragma unroll
    for (int k = 0; k < 2; ++k) {
        const int idx = t * 2 + k;
        const int j = idx >> 7, o = idx & 127;
        const float2 w = ti[j];
        wvT[o][j] = w.x * ys[(j * 2 + 0) * kD + o] + w.y * ys[(j * 2 + 1) * kD + o];
    }
    __syncthreads();

    const int hh = t >> 7, o = t & 127;
    const float* Wm = hh ? w2m : w1m;
    const float bias = hh ? b2[o] : b1[o];
    float a0 = bias, a1 = bias, a2 = bias, a3 = bias;
    #pragma unroll 4
    for (int d = 0; d < kD; ++d) {
        const float w = Wm[d * kD + o];
        const float4 xv = *(const float4*)&wvT[d][0];
        a0 = fmaf(xv.x, w, a0);
        a1 = fmaf(xv.y, w, a1);
        a2 = fmaf(xv.z, w, a2);
        a3 = fmaf(xv.w, w, a3);
    }
    if (hh) { vvs[0][o] = a0; vvs[1][o] = a1; vvs[2][o] = a2; vvs[3][o] = a3; }
    __syncthreads();
    if (!hh) {
        float gg[4] = {a0, a1, a2, a3};
        #pragma unroll
        for (int j = 0; j < 4; ++j) {
            const float g = gg[j];
            const float r = g * (1.f / (1.f + __expf(-g))) * vvs[j][o];
            os[j][o] = r;
            out_avg[(size_t)(tok0 + j) * kD + o] = r;
        }
    }
    __syncthreads();

    // variance -> consensus
    const int wv = t >> 6, ln = t & 63;
    const float2 w = ti[wv];
    float s = 0.f;
    #pragma unroll
    for (int k = 0; k < 2; ++k) {
        const int oo = ln * 2 + k;
        const float ot = os[wv][oo];
        const float d0 = ys[(wv * 2 + 0) * kD + oo] - ot;
        const float d1 = ys[(wv * 2 + 1) * kD + oo] - ot;
        s += w.x * d0 * d0 + w.y * d1 * d1;
    }
    #pragma unroll
    for (int sft = 1; sft < 64; sft <<= 1) s += __shfl_xor(s, sft);
    if (ln == 0) out_cons[tok0 + wv] = __expf(-s * (1.0f / (float)kD));
}

extern "C" void kernel_launch(void* const* d_in, const int* in_sizes, int n_in,
                              void* d_out, int out_size, void* d_ws, size_t ws_size,
                              hipStream_t stream) {
    const float*  x        = (const float*)d_in[0];
    const float*  gate_w   = (const float*)d_in[1];
    const float*  gate_b   = (const float*)d_in[2];
    const float*  expert_w = (const float*)d_in[3];
    const float*  w1m      = (const float*)d_in[4];
    const float*  b1       = (const float*)d_in[5];
    const float*  w2m      = (const float*)d_in[6];
    const float*  b2       = (const float*)d_in[7];

    float* out_avg  = (float*)d_out;
    float* out_cons = out_avg + (size_t)kTok * kD;

    char*   ws      = (char*)d_ws;
    float2* tokinfo = (float2*)ws;                 // 16 KB
    int*    top2    = (int*)(ws + 16384);          // 8 KB
    int*    barrier = (int*)(ws + 24576);          // 4 B (padded)
    float*  ybuf    = (float*)(ws + 32768);        // 2 MB

    k_gate <<<kTok / 4, 256, 0, stream>>>(x, gate_w, gate_b, tokinfo, top2, barrier);
    k_fused<<<kGrid2,   256, 0, stream>>>(x, expert_w, top2, tokinfo,
                                          w1m, b1, w2m, b2,
                                          ybuf, barrier, out_avg, out_cons);
}

// Round 5
// 47.527 us; speedup vs baseline: 2.6649x; 2.6649x over previous
//
#include <hip/hip_runtime.h>
#include <math.h>

constexpr int kD   = 128;
constexpr int kE   = 256;
constexpr int kTok = 2048;

// One fused kernel: 512 blocks x 256 threads; each block owns 4 tokens.
// Phases: gate -> top2 -> expert matvecs (streamed, float2) -> combine ->
// SwiGLU -> consensus. No atomics, no global scratch, 1 graph node.
__global__ __launch_bounds__(256) void moe_one(
    const float* __restrict__ x, const float* __restrict__ gate_w,
    const float* __restrict__ gate_b, const float* __restrict__ expert_w,
    const float* __restrict__ w1m, const float* __restrict__ b1,
    const float* __restrict__ w2m, const float* __restrict__ b2,
    float* __restrict__ out_avg, float* __restrict__ out_cons)
{
    const int b  = blockIdx.x;
    const int t  = threadIdx.x;
    const int wv = t >> 6, ln = t & 63;
    const int tok0 = b * 4;

    __shared__ float  xsT[kD][4];     // x transposed: xsT[d][token]
    __shared__ float  partf[4][4];    // [wave][token] partials
    __shared__ int    parti[4][4];
    __shared__ int    pi0s[4];
    __shared__ float  pv0s[4];
    __shared__ float2 ti[4];          // renormalized top-2 weights
    __shared__ int    e0s[4], e1s[4]; // top-2 expert ids
    __shared__ float  ys[8][kD];      // y per (token,slot)
    __shared__ float  wavT[kD][4];    // weighted avg, transposed
    __shared__ float  vvs[4][kD];     // w2 path
    __shared__ float  os[4][kD];      // final outputs

    // ---- load x rows (transposed into LDS) ----
    {
        const float2 v = *(const float2*)(x + ((size_t)(tok0 + wv)) * kD + ln * 2);
        xsT[ln * 2 + 0][wv] = v.x;
        xsT[ln * 2 + 1][wv] = v.y;
    }
    __syncthreads();

    // ---- gate logits: thread t = expert t, 4 tokens ----
    float lg[4];
    {
        const float bias = gate_b[t];
        lg[0] = lg[1] = lg[2] = lg[3] = bias;
    }
    #pragma unroll 8
    for (int d = 0; d < kD; ++d) {
        const float w = gate_w[d * kE + t];
        const float4 xv = *(const float4*)&xsT[d][0];
        lg[0] = fmaf(xv.x, w, lg[0]);
        lg[1] = fmaf(xv.y, w, lg[1]);
        lg[2] = fmaf(xv.z, w, lg[2]);
        lg[3] = fmaf(xv.w, w, lg[3]);
    }

    // ---- softmax max ----
    float m[4];
    #pragma unroll
    for (int j = 0; j < 4; ++j) m[j] = lg[j];
    #pragma unroll
    for (int s = 1; s < 64; s <<= 1) {
        #pragma unroll
        for (int j = 0; j < 4; ++j) m[j] = fmaxf(m[j], __shfl_xor(m[j], s));
    }
    if (ln == 0) {
        #pragma unroll
        for (int j = 0; j < 4; ++j) partf[wv][j] = m[j];
    }
    __syncthreads();
    float mx[4];
    #pragma unroll
    for (int j = 0; j < 4; ++j)
        mx[j] = fmaxf(fmaxf(partf[0][j], partf[1][j]), fmaxf(partf[2][j], partf[3][j]));
    __syncthreads();

    // ---- softmax sum ----
    float ex[4], sm[4];
    #pragma unroll
    for (int j = 0; j < 4; ++j) { ex[j] = __expf(lg[j] - mx[j]); sm[j] = ex[j]; }
    #pragma unroll
    for (int s = 1; s < 64; s <<= 1) {
        #pragma unroll
        for (int j = 0; j < 4; ++j) sm[j] += __shfl_xor(sm[j], s);
    }
    if (ln == 0) {
        #pragma unroll
        for (int j = 0; j < 4; ++j) partf[wv][j] = sm[j];
    }
    __syncthreads();
    float p[4];
    #pragma unroll
    for (int j = 0; j < 4; ++j) {
        const float tot = partf[0][j] + partf[1][j] + partf[2][j] + partf[3][j];
        p[j] = ex[j] / tot;
    }
    __syncthreads();

    // ---- argmax pass 1 (ties -> lower index) ----
    float v[4]; int ix[4];
    #pragma unroll
    for (int j = 0; j < 4; ++j) { v[j] = p[j]; ix[j] = t; }
    #pragma unroll
    for (int s = 1; s < 64; s <<= 1) {
        #pragma unroll
        for (int j = 0; j < 4; ++j) {
            const float ov = __shfl_xor(v[j], s);
            const int   oi = __shfl_xor(ix[j], s);
            if (ov > v[j] || (ov == v[j] && oi < ix[j])) { v[j] = ov; ix[j] = oi; }
        }
    }
    if (ln == 0) {
        #pragma unroll
        for (int j = 0; j < 4; ++j) { partf[wv][j] = v[j]; parti[wv][j] = ix[j]; }
    }
    __syncthreads();
    if (t < 4) {
        const int j = t;
        float bv = partf[0][j]; int bi = parti[0][j];
        #pragma unroll
        for (int w = 1; w < 4; ++w) {
            const float ov = partf[w][j]; const int oi = parti[w][j];
            if (ov > bv || (ov == bv && oi < bi)) { bv = ov; bi = oi; }
        }
        pv0s[j] = bv; pi0s[j] = bi;
    }
    __syncthreads();

    // ---- argmax pass 2 (mask winner) ----
    #pragma unroll
    for (int j = 0; j < 4; ++j) {
        v[j] = (t == pi0s[j]) ? -INFINITY : p[j];
        ix[j] = t;
    }
    #pragma unroll
    for (int s = 1; s < 64; s <<= 1) {
        #pragma unroll
        for (int j = 0; j < 4; ++j) {
            const float ov = __shfl_xor(v[j], s);
            const int   oi = __shfl_xor(ix[j], s);
            if (ov > v[j] || (ov == v[j] && oi < ix[j])) { v[j] = ov; ix[j] = oi; }
        }
    }
    if (ln == 0) {
        #pragma unroll
        for (int j = 0; j < 4; ++j) { partf[wv][j] = v[j]; parti[wv][j] = ix[j]; }
    }
    __syncthreads();
    if (t < 4) {
        const int j = t;
        float bv = partf[0][j]; int bi = parti[0][j];
        #pragma unroll
        for (int w = 1; w < 4; ++w) {
            const float ov = partf[w][j]; const int oi = parti[w][j];
            if (ov > bv || (ov == bv && oi < bi)) { bv = ov; bi = oi; }
        }
        const float v0 = pv0s[j], v1 = bv;
        const float den = v0 + v1 + 1e-6f;
        ti[j]  = make_float2(v0 / den, v1 / den);
        e0s[j] = pi0s[j];
        e1s[j] = bi;
    }
    __syncthreads();

    // ---- expert matvecs: wave wv handles pair pr = r*4+wv ----
    // pair pr -> token j = pr>>1, slot sl = pr&1; x broadcast is wave-uniform.
    #pragma unroll
    for (int r = 0; r < 2; ++r) {
        const int pr = r * 4 + wv;
        const int j  = pr >> 1;
        const int sl = pr & 1;
        const int e  = sl ? e1s[j] : e0s[j];
        const float* Ew = expert_w + (size_t)e * kD * kD + ln * 2;
        float ax = 0.f, ay = 0.f;
        #pragma unroll 8
        for (int d = 0; d < kD; ++d) {
            const float xv = xsT[d][j];
            const float2 w2v = *(const float2*)&Ew[(size_t)d * kD];
            ax = fmaf(w2v.x, xv, ax);
            ay = fmaf(w2v.y, xv, ay);
        }
        ys[pr][ln * 2 + 0] = ax;
        ys[pr][ln * 2 + 1] = ay;
    }
    __syncthreads();

    // ---- combine: weighted avg (transposed) ----
    #pragma unroll
    for (int k = 0; k < 2; ++k) {
        const int idx = t * 2 + k;
        const int j = idx >> 7, o = idx & 127;
        const float2 w = ti[j];
        wavT[o][j] = w.x * ys[j * 2 + 0][o] + w.y * ys[j * 2 + 1][o];
    }
    __syncthreads();

    // ---- SwiGLU: half 0 -> w1 path, half 1 -> w2 path, 4 tokens each ----
    const int h = t >> 7, o = t & 127;
    const float* Wm = h ? w2m : w1m;
    const float bias = h ? b2[o] : b1[o];
    float a0 = bias, a1 = bias, a2 = bias, a3 = bias;
    #pragma unroll 4
    for (int d = 0; d < kD; ++d) {
        const float w = Wm[d * kD + o];
        const float4 xv = *(const float4*)&wavT[d][0];
        a0 = fmaf(xv.x, w, a0);
        a1 = fmaf(xv.y, w, a1);
        a2 = fmaf(xv.z, w, a2);
        a3 = fmaf(xv.w, w, a3);
    }
    if (h) { vvs[0][o] = a0; vvs[1][o] = a1; vvs[2][o] = a2; vvs[3][o] = a3; }
    __syncthreads();
    if (!h) {
        float gg[4] = {a0, a1, a2, a3};
        #pragma unroll
        for (int j = 0; j < 4; ++j) {
            const float g = gg[j];
            const float r = g * (1.f / (1.f + __expf(-g))) * vvs[j][o];
            os[j][o] = r;
            out_avg[(size_t)(tok0 + j) * kD + o] = r;
        }
    }
    __syncthreads();

    // ---- variance -> consensus: wave wv = token wv ----
    {
        const float2 w = ti[wv];
        float s = 0.f;
        #pragma unroll
        for (int k = 0; k < 2; ++k) {
            const int oo = ln * 2 + k;
            const float ot = os[wv][oo];
            const float d0 = ys[wv * 2 + 0][oo] - ot;
            const float d1 = ys[wv * 2 + 1][oo] - ot;
            s += w.x * d0 * d0 + w.y * d1 * d1;
        }
        #pragma unroll
        for (int sft = 1; sft < 64; sft <<= 1) s += __shfl_xor(s, sft);
        if (ln == 0) out_cons[tok0 + wv] = __expf(-s * (1.0f / (float)kD));
    }
}

extern "C" void kernel_launch(void* const* d_in, const int* in_sizes, int n_in,
                              void* d_out, int out_size, void* d_ws, size_t ws_size,
                              hipStream_t stream) {
    const float* x        = (const float*)d_in[0];
    const float* gate_w   = (const float*)d_in[1];
    const float* gate_b   = (const float*)d_in[2];
    const float* expert_w = (const float*)d_in[3];
    const float* w1m      = (const float*)d_in[4];
    const float* b1       = (const float*)d_in[5];
    const float* w2m      = (const float*)d_in[6];
    const float* b2       = (const float*)d_in[7];

    float* out_avg  = (float*)d_out;
    float* out_cons = out_avg + (size_t)kTok * kD;

    moe_one<<<kTok / 4, 256, 0, stream>>>(x, gate_w, gate_b, expert_w,
                                          w1m, b1, w2m, b2, out_avg, out_cons);
}

// Round 6
// 45.750 us; speedup vs baseline: 2.7683x; 1.0388x over previous
//
#include <hip/hip_runtime.h>
#include <math.h>

constexpr int kD   = 128;
constexpr int kE   = 256;
constexpr int kTok = 2048;

// One fused kernel: 512 blocks x 1024 threads (16 waves); block owns 4 tokens.
// 2 blocks/CU -> 32 waves/CU (full occupancy). Phases: gate -> top2 ->
// expert matvecs (2 waves per (token,slot) pair) -> combine -> SwiGLU ->
// consensus. No atomics, no scratch, 1 graph node.
__global__ __launch_bounds__(1024, 8) void moe_one(
    const float* __restrict__ x, const float* __restrict__ gate_w,
    const float* __restrict__ gate_b, const float* __restrict__ expert_w,
    const float* __restrict__ w1m, const float* __restrict__ b1,
    const float* __restrict__ w2m, const float* __restrict__ b2,
    float* __restrict__ out_avg, float* __restrict__ out_cons)
{
    const int b  = blockIdx.x;
    const int t  = threadIdx.x;
    const int W  = t >> 6;        // wave 0..15
    const int ln = t & 63;
    const int tok0 = b * 4;

    __shared__ float  xsT[kD][5];     // pad 5: conflict-free transpose write
    __shared__ float  partf[4][4];    // [token][wave-in-group]
    __shared__ int    parti[4][4];
    __shared__ float  pv0s[4];
    __shared__ int    pi0s[4];
    __shared__ float2 ti[4];
    __shared__ int    e01[4];         // e0 | e1<<8
    __shared__ float  ys[8][kD];      // y per (token,slot)
    __shared__ float  wavT[kD][5];
    __shared__ float  vvs[4][kD];
    __shared__ float  os[4][kD];
    __shared__ float  cparts[4][2];

    // ---- load x (coalesced, transposed into LDS) ----
    if (t < 512) {
        const int j = t >> 7, d = t & 127;
        xsT[d][j] = x[(size_t)(tok0 + j) * kD + d];
    }
    __syncthreads();

    // ---- gate: thread -> (expert ge, token gj); 1 logit each ----
    const int ge = t & 255;
    const int gj = t >> 8;
    const int lw = W & 3;             // wave within token group
    float logit = gate_b[ge];
    #pragma unroll 8
    for (int d = 0; d < kD; ++d)
        logit = fmaf(xsT[d][gj], gate_w[d * kE + ge], logit);

    // ---- softmax max (wave butterfly + 4-wave LDS combine per token) ----
    float m = logit;
    #pragma unroll
    for (int s = 1; s < 64; s <<= 1) m = fmaxf(m, __shfl_xor(m, s));
    if (ln == 0) partf[gj][lw] = m;
    __syncthreads();
    const float mx = fmaxf(fmaxf(partf[gj][0], partf[gj][1]),
                           fmaxf(partf[gj][2], partf[gj][3]));
    __syncthreads();

    // ---- softmax sum ----
    const float ex = __expf(logit - mx);
    float sm = ex;
    #pragma unroll
    for (int s = 1; s < 64; s <<= 1) sm += __shfl_xor(sm, s);
    if (ln == 0) partf[gj][lw] = sm;
    __syncthreads();
    const float tot = partf[gj][0] + partf[gj][1] + partf[gj][2] + partf[gj][3];
    const float p = ex / tot;
    __syncthreads();

    // ---- argmax pass 1 (ties -> lower expert index) ----
    float v = p; int ix = ge;
    #pragma unroll
    for (int s = 1; s < 64; s <<= 1) {
        const float ov = __shfl_xor(v, s);
        const int   oi = __shfl_xor(ix, s);
        if (ov > v || (ov == v && oi < ix)) { v = ov; ix = oi; }
    }
    if (ln == 0) { partf[gj][lw] = v; parti[gj][lw] = ix; }
    __syncthreads();
    if ((t & 255) == 0) {
        float bv = partf[gj][0]; int bi = parti[gj][0];
        #pragma unroll
        for (int w = 1; w < 4; ++w) {
            const float ov = partf[gj][w]; const int oi = parti[gj][w];
            if (ov > bv || (ov == bv && oi < bi)) { bv = ov; bi = oi; }
        }
        pv0s[gj] = bv; pi0s[gj] = bi;
    }
    __syncthreads();

    // ---- argmax pass 2 (mask winner) ----
    v = (ge == pi0s[gj]) ? -INFINITY : p; ix = ge;
    #pragma unroll
    for (int s = 1; s < 64; s <<= 1) {
        const float ov = __shfl_xor(v, s);
        const int   oi = __shfl_xor(ix, s);
        if (ov > v || (ov == v && oi < ix)) { v = ov; ix = oi; }
    }
    if (ln == 0) { partf[gj][lw] = v; parti[gj][lw] = ix; }
    __syncthreads();
    if ((t & 255) == 0) {
        float bv = partf[gj][0]; int bi = parti[gj][0];
        #pragma unroll
        for (int w = 1; w < 4; ++w) {
            const float ov = partf[gj][w]; const int oi = parti[gj][w];
            if (ov > bv || (ov == bv && oi < bi)) { bv = ov; bi = oi; }
        }
        const float v0 = pv0s[gj], v1 = bv;
        const float den = v0 + v1 + 1e-6f;
        ti[gj]  = make_float2(v0 / den, v1 / den);
        e01[gj] = pi0s[gj] | (bi << 8);
    }
    __syncthreads();

    // ---- expert matvecs: 2 waves per (token,slot) pair; lane = 1 column ----
    {
        const int pr = W >> 1;            // pair 0..7
        const int hf = W & 1;             // column half
        const int ej = pr >> 1;           // token
        const int sl = pr & 1;            // slot
        const int pk = e01[ej];
        const int e  = sl ? ((pk >> 8) & 255) : (pk & 255);
        const float* Ew = expert_w + (size_t)e * kD * kD + hf * 64 + ln;
        float acc = 0.f;
        #pragma unroll 8
        for (int d = 0; d < kD; ++d)
            acc = fmaf(Ew[(size_t)d * kD], xsT[d][ej], acc);
        ys[pr][hf * 64 + ln] = acc;
    }
    __syncthreads();

    // ---- combine: weighted avg (transposed) ----
    if (t < 512) {
        const int j = t >> 7, o = t & 127;
        const float2 w = ti[j];
        wavT[o][j] = w.x * ys[2 * j][o] + w.y * ys[2 * j + 1][o];
    }
    __syncthreads();

    // ---- SwiGLU: thread -> (path h, token jg, output o) ----
    {
        const int h = t >> 9, rem = t & 511, jg = rem >> 7, o = rem & 127;
        const float* Wm = h ? w2m : w1m;
        float acc = h ? b2[o] : b1[o];
        #pragma unroll 8
        for (int d = 0; d < kD; ++d)
            acc = fmaf(wavT[d][jg], Wm[d * kD + o], acc);
        if (h) vvs[jg][o] = acc;
        __syncthreads();
        if (!h) {
            const float g = acc;
            const float r = g * (1.f / (1.f + __expf(-g))) * vvs[jg][o];
            os[jg][o] = r;
            out_avg[(size_t)(tok0 + jg) * kD + o] = r;
        }
    }
    __syncthreads();

    // ---- variance -> consensus: 2 waves per token ----
    if (t < 512) {
        const int j = W >> 1;
        const int o = (W & 1) * 64 + ln;
        const float2 w = ti[j];
        const float ot = os[j][o];
        const float d0 = ys[2 * j][o] - ot;
        const float d1 = ys[2 * j + 1][o] - ot;
        float s = w.x * d0 * d0 + w.y * d1 * d1;
        #pragma unroll
        for (int sft = 1; sft < 64; sft <<= 1) s += __shfl_xor(s, sft);
        if (ln == 0) cparts[j][W & 1] = s;
    }
    __syncthreads();
    if (t < 4)
        out_cons[tok0 + t] = __expf(-(cparts[t][0] + cparts[t][1]) * (1.0f / (float)kD));
}

extern "C" void kernel_launch(void* const* d_in, const int* in_sizes, int n_in,
                              void* d_out, int out_size, void* d_ws, size_t ws_size,
                              hipStream_t stream) {
    const float* x        = (const float*)d_in[0];
    const float* gate_w   = (const float*)d_in[1];
    const float* gate_b   = (const float*)d_in[2];
    const float* expert_w = (const float*)d_in[3];
    const float* w1m      = (const float*)d_in[4];
    const float* b1       = (const float*)d_in[5];
    const float* w2m      = (const float*)d_in[6];
    const float* b2       = (const float*)d_in[7];

    float* out_avg  = (float*)d_out;
    float* out_cons = out_avg + (size_t)kTok * kD;

    moe_one<<<kTok / 4, 1024, 0, stream>>>(x, gate_w, gate_b, expert_w,
                                           w1m, b1, w2m, b2, out_avg, out_cons);
}

// Round 7
// 39.541 us; speedup vs baseline: 3.2031x; 1.1570x over previous
//
#include <hip/hip_runtime.h>
#include <math.h>

constexpr int kD   = 128;
constexpr int kE   = 256;
constexpr int kTok = 2048;

// ---------------- K1: gate (logits -> softmax -> top2) ----------------------
// 512 blocks x 256 threads; block handles 4 tokens; thread t = expert t.
__global__ __launch_bounds__(256) void k_gate(
    const float* __restrict__ x, const float* __restrict__ gate_w,
    const float* __restrict__ gate_b,
    float2* __restrict__ tokinfo, int* __restrict__ top2)
{
    const int b  = blockIdx.x;
    const int t  = threadIdx.x;
    const int wv = t >> 6, ln = t & 63;

    __shared__ float xsT[kD][4];
    __shared__ float partf[4][4];
    __shared__ int   parti[4][4];
    __shared__ int   pi0s[4];
    __shared__ float pv0s[4];

    {
        const float2 v = *(const float2*)(x + ((size_t)(b * 4 + wv)) * kD + ln * 2);
        xsT[ln * 2 + 0][wv] = v.x;
        xsT[ln * 2 + 1][wv] = v.y;
    }
    __syncthreads();

    float lg[4];
    {
        const float bias = gate_b[t];
        lg[0] = lg[1] = lg[2] = lg[3] = bias;
    }
    #pragma unroll 8
    for (int d = 0; d < kD; ++d) {
        const float w = gate_w[d * kE + t];
        const float4 xv = *(const float4*)&xsT[d][0];
        lg[0] = fmaf(xv.x, w, lg[0]);
        lg[1] = fmaf(xv.y, w, lg[1]);
        lg[2] = fmaf(xv.z, w, lg[2]);
        lg[3] = fmaf(xv.w, w, lg[3]);
    }

    // max over experts
    float m[4];
    #pragma unroll
    for (int j = 0; j < 4; ++j) m[j] = lg[j];
    #pragma unroll
    for (int s = 1; s < 64; s <<= 1) {
        #pragma unroll
        for (int j = 0; j < 4; ++j) m[j] = fmaxf(m[j], __shfl_xor(m[j], s));
    }
    if (ln == 0) {
        #pragma unroll
        for (int j = 0; j < 4; ++j) partf[wv][j] = m[j];
    }
    __syncthreads();
    float mx[4];
    #pragma unroll
    for (int j = 0; j < 4; ++j)
        mx[j] = fmaxf(fmaxf(partf[0][j], partf[1][j]), fmaxf(partf[2][j], partf[3][j]));
    __syncthreads();

    // sum of exp
    float ex[4], sm[4];
    #pragma unroll
    for (int j = 0; j < 4; ++j) { ex[j] = __expf(lg[j] - mx[j]); sm[j] = ex[j]; }
    #pragma unroll
    for (int s = 1; s < 64; s <<= 1) {
        #pragma unroll
        for (int j = 0; j < 4; ++j) sm[j] += __shfl_xor(sm[j], s);
    }
    if (ln == 0) {
        #pragma unroll
        for (int j = 0; j < 4; ++j) partf[wv][j] = sm[j];
    }
    __syncthreads();
    float p[4];
    #pragma unroll
    for (int j = 0; j < 4; ++j) {
        const float tot = partf[0][j] + partf[1][j] + partf[2][j] + partf[3][j];
        p[j] = ex[j] / tot;
    }
    __syncthreads();

    // argmax pass 1 (ties -> lower index)
    float v[4]; int ix[4];
    #pragma unroll
    for (int j = 0; j < 4; ++j) { v[j] = p[j]; ix[j] = t; }
    #pragma unroll
    for (int s = 1; s < 64; s <<= 1) {
        #pragma unroll
        for (int j = 0; j < 4; ++j) {
            const float ov = __shfl_xor(v[j], s);
            const int   oi = __shfl_xor(ix[j], s);
            if (ov > v[j] || (ov == v[j] && oi < ix[j])) { v[j] = ov; ix[j] = oi; }
        }
    }
    if (ln == 0) {
        #pragma unroll
        for (int j = 0; j < 4; ++j) { partf[wv][j] = v[j]; parti[wv][j] = ix[j]; }
    }
    __syncthreads();
    if (t < 4) {
        const int j = t;
        float bv = partf[0][j]; int bi = parti[0][j];
        #pragma unroll
        for (int w = 1; w < 4; ++w) {
            const float ov = partf[w][j]; const int oi = parti[w][j];
            if (ov > bv || (ov == bv && oi < bi)) { bv = ov; bi = oi; }
        }
        pv0s[j] = bv; pi0s[j] = bi;
    }
    __syncthreads();

    // argmax pass 2 (mask winner)
    #pragma unroll
    for (int j = 0; j < 4; ++j) {
        v[j] = (t == pi0s[j]) ? -INFINITY : p[j];
        ix[j] = t;
    }
    #pragma unroll
    for (int s = 1; s < 64; s <<= 1) {
        #pragma unroll
        for (int j = 0; j < 4; ++j) {
            const float ov = __shfl_xor(v[j], s);
            const int   oi = __shfl_xor(ix[j], s);
            if (ov > v[j] || (ov == v[j] && oi < ix[j])) { v[j] = ov; ix[j] = oi; }
        }
    }
    if (ln == 0) {
        #pragma unroll
        for (int j = 0; j < 4; ++j) { partf[wv][j] = v[j]; parti[wv][j] = ix[j]; }
    }
    __syncthreads();
    if (t < 4) {
        const int j = t;
        float bv = partf[0][j]; int bi = parti[0][j];
        #pragma unroll
        for (int w = 1; w < 4; ++w) {
            const float ov = partf[w][j]; const int oi = parti[w][j];
            if (ov > bv || (ov == bv && oi < bi)) { bv = ov; bi = oi; }
        }
        const int tok = b * 4 + j;
        const float v0 = pv0s[j], v1 = bv;
        const float den = v0 + v1 + 1e-6f;
        tokinfo[tok] = make_float2(v0 / den, v1 / den);
        top2[tok] = pi0s[j] | (bi << 8);
    }
}

// ---------------- K2: expert-grouped matvecs --------------------------------
// 512 blocks = (expert e, output-half hf) x 1024 threads (16 waves).
// 2 blocks/CU, 32 waves/CU. W-half (32 KB) staged once per block ->
// expert_w L2-fill traffic = compulsory 16.8 MB total.
__global__ __launch_bounds__(1024) void k_expert(
    const float* __restrict__ x, const float* __restrict__ expert_w,
    const int* __restrict__ top2, float* __restrict__ ybuf)
{
    const int e  = blockIdx.x >> 1;
    const int hf = blockIdx.x & 1;
    const int t  = threadIdx.x;

    __shared__ float W[kD][64];    // 32 KB, cols hf*64 .. hf*64+63
    __shared__ float xs[16][kD];   // 8 KB: x rows for current round
    __shared__ int   llist[kTok];  // 8 KB
    __shared__ int   lcount;

    if (t == 0) lcount = 0;
    __syncthreads();

    // build local token list from routing (8 KB, L2-hot)
    #pragma unroll
    for (int k = 0; k < 2; ++k) {
        const int i = k * 1024 + t;
        const int pk = top2[i];
        if ((pk & 255) == e)        llist[atomicAdd(&lcount, 1)] = i * 2;
        if (((pk >> 8) & 255) == e) llist[atomicAdd(&lcount, 1)] = i * 2 + 1;
    }

    // stage W half: W[r][c] = expert_w[e][r][hf*64 + c]
    {
        const float* Wg = expert_w + (size_t)e * kD * kD + hf * 64;
        #pragma unroll
        for (int k = 0; k < 2; ++k) {
            const int f  = k * 1024 + t;     // float4 id 0..2047
            const int r  = f >> 4;           // 16 float4 per 64-col row
            const int c4 = (f & 15) * 4;
            *(float4*)&W[r][c4] = *(const float4*)&Wg[(size_t)r * kD + c4];
        }
    }
    __syncthreads();
    const int n = lcount;

    const int Wv = t >> 6, ln = t & 63;
    for (int base = 0; base < n; base += 16) {
        const int m = min(16, n - base);
        // cooperative load of m x-rows (coalesced 512 B per row)
        for (int i = t; i < m * kD; i += 1024) {
            const int row = i >> 7, d = i & 127;
            const int ev = llist[base + row];
            xs[row][d] = x[(size_t)(ev >> 1) * kD + d];
        }
        __syncthreads();

        const int idx = base + Wv;
        if (idx < n) {
            float acc = 0.f;
            #pragma unroll 8
            for (int d = 0; d < kD; ++d)
                acc = fmaf(xs[Wv][d], W[d][ln], acc);   // xs: broadcast, W: 2-way (free)
            const int ev = llist[idx];
            ybuf[((size_t)(ev >> 1) * 2 + (ev & 1)) * kD + hf * 64 + ln] = acc;
        }
        __syncthreads();
    }
}

// ---------------- K3: combine + SwiGLU + consensus --------------------------
// 512 blocks x 256 threads; block handles 4 tokens.
__global__ __launch_bounds__(256) void k_swiglu(
    const float* __restrict__ ybuf, const float2* __restrict__ tokinfo,
    const float* __restrict__ w1m, const float* __restrict__ b1,
    const float* __restrict__ w2m, const float* __restrict__ b2,
    float* __restrict__ out_avg, float* __restrict__ out_cons)
{
    const int b = blockIdx.x;
    const int t = threadIdx.x;
    const int tok0 = b * 4;

    __shared__ float  ys[4 * 2 * kD];
    __shared__ float  wvT[kD][4];
    __shared__ float  vv[4][kD];
    __shared__ float  os[4][kD];
    __shared__ float2 ti[4];

    *(float4*)&ys[t * 4] = *(const float4*)&ybuf[(size_t)tok0 * 2 * kD + t * 4];
    if (t < 4) ti[t] = tokinfo[tok0 + t];
    __syncthreads();

    #pragma unroll
    for (int k = 0; k < 2; ++k) {
        const int idx = t * 2 + k;
        const int j = idx >> 7, o = idx & 127;
        const float2 w = ti[j];
        wvT[o][j] = w.x * ys[(j * 2 + 0) * kD + o] + w.y * ys[(j * 2 + 1) * kD + o];
    }
    __syncthreads();

    const int h = t >> 7, o = t & 127;
    const float* Wm = h ? w2m : w1m;
    const float bias = h ? b2[o] : b1[o];
    float a0 = bias, a1 = bias, a2 = bias, a3 = bias;
    #pragma unroll 4
    for (int d = 0; d < kD; ++d) {
        const float w = Wm[d * kD + o];
        const float4 xv = *(const float4*)&wvT[d][0];
        a0 = fmaf(xv.x, w, a0);
        a1 = fmaf(xv.y, w, a1);
        a2 = fmaf(xv.z, w, a2);
        a3 = fmaf(xv.w, w, a3);
    }
    if (h) { vv[0][o] = a0; vv[1][o] = a1; vv[2][o] = a2; vv[3][o] = a3; }
    __syncthreads();
    if (!h) {
        float gg[4] = {a0, a1, a2, a3};
        #pragma unroll
        for (int j = 0; j < 4; ++j) {
            const float g = gg[j];
            const float r = g * (1.f / (1.f + __expf(-g))) * vv[j][o];
            os[j][o] = r;
            out_avg[(size_t)(tok0 + j) * kD + o] = r;
        }
    }
    __syncthreads();

    const int wv = t >> 6, ln = t & 63;
    const float2 w = ti[wv];
    float s = 0.f;
    #pragma unroll
    for (int k = 0; k < 2; ++k) {
        const int oo = ln * 2 + k;
        const float ot = os[wv][oo];
        const float d0 = ys[(wv * 2 + 0) * kD + oo] - ot;
        const float d1 = ys[(wv * 2 + 1) * kD + oo] - ot;
        s += w.x * d0 * d0 + w.y * d1 * d1;
    }
    #pragma unroll
    for (int sft = 1; sft < 64; sft <<= 1) s += __shfl_xor(s, sft);
    if (ln == 0) out_cons[tok0 + wv] = __expf(-s * (1.0f / (float)kD));
}

extern "C" void kernel_launch(void* const* d_in, const int* in_sizes, int n_in,
                              void* d_out, int out_size, void* d_ws, size_t ws_size,
                              hipStream_t stream) {
    const float*  x        = (const float*)d_in[0];
    const float*  gate_w   = (const float*)d_in[1];
    const float*  gate_b   = (const float*)d_in[2];
    const float*  expert_w = (const float*)d_in[3];
    const float*  w1m      = (const float*)d_in[4];
    const float*  b1       = (const float*)d_in[5];
    const float*  w2m      = (const float*)d_in[6];
    const float*  b2       = (const float*)d_in[7];

    float* out_avg  = (float*)d_out;
    float* out_cons = out_avg + (size_t)kTok * kD;

    char*   ws      = (char*)d_ws;
    float2* tokinfo = (float2*)ws;                 // 16 KB
    int*    top2    = (int*)(ws + 16384);          // 8 KB
    float*  ybuf    = (float*)(ws + 32768);        // 2 MB

    k_gate  <<<kTok / 4, 256,  0, stream>>>(x, gate_w, gate_b, tokinfo, top2);
    k_expert<<<kE * 2,   1024, 0, stream>>>(x, expert_w, top2, ybuf);
    k_swiglu<<<kTok / 4, 256,  0, stream>>>(ybuf, tokinfo, w1m, b1, w2m, b2, out_avg, out_cons);
}